// Round 2
// baseline (1351.463 us; speedup 1.0000x reference)
//
#include <hip/hip_runtime.h>
#include <hip/hip_bf16.h>

#define BB 8
#define TT 4
#define NN 4096
#define UU 64
#define EE 65536
#define BN (BB*NN)   // 32768
#define CAP 64
#define NEG 0.2f

// ws layout (float offsets)
#define OFF_XT   0         // 12*BN   (t,f,row)
#define OFF_HT   393216    // 64*BN   (u,row)
#define OFF_HP   2490368   // BN*64   row-major h' ; later reused as rsT (u,row)
#define OFF_ES   4587520   // BN
#define OFF_ED   4620288   // BN
#define OFF_ST   4653056   // 64*BN   (u,row)
#define OFF_CNT  6750208   // NN ints
#define OFF_SLOT 6754304   // NN*CAP ints  (ends 7016448 floats = 28.07 MB)

__global__ __launch_bounds__(256) void k_conv_x(const float* x, float* xT) {
  int i = blockIdx.x * 256 + threadIdx.x;     // < 12*BN
  int r = i & (BN - 1);
  int tf = i >> 15;
  int t = tf / 3, f = tf - 3 * t;
  int b = r >> 12, n = r & (NN - 1);
  xT[i] = x[(((b * TT + t) * NN + n) * 3) + f];
}

__global__ __launch_bounds__(256) void k_fill(const int* src, const int* dst,
                                              int* cnt, int* slot) {
  int i = blockIdx.x * 256 + threadIdx.x;
  if (i < EE) {
    int d = dst[i];
    int p = atomicAdd(&cnt[d], 1);
    if (p < CAP) slot[d * CAP + p] = src[i];
  } else if (i < EE + NN) {
    int n = i - EE;
    int p = atomicAdd(&cnt[n], 1);
    if (p < CAP) slot[n * CAP + p] = n;
  }
}

// h' = [h, x_t] @ gat_W ; es = h'.a_src ; ed = h'.a_dst
__global__ __launch_bounds__(256) void k_gat(float* ws, const float* gW,
                                             const float* as_, const float* ad_,
                                             int t) {
  const float* hT = ws + OFF_HT;
  const float* xT = ws + OFF_XT;
  float* hp = ws + OFF_HP;
  float* es = ws + OFF_ES;
  float* ed = ws + OFF_ED;
  int row = blockIdx.x * 256 + threadIdx.x;
  float xv[3];
#pragma unroll
  for (int k = 0; k < 3; ++k) xv[k] = xT[(t * 3 + k) * BN + row];
  float esa = 0.f, eda = 0.f;
#pragma unroll 1
  for (int uc = 0; uc < 4; ++uc) {
    const int u0 = uc * 16;
    float acc[16];
#pragma unroll
    for (int j = 0; j < 16; ++j) acc[j] = 0.f;
    for (int k = 0; k < 64; ++k) {
      float ck = hT[k * BN + row];
#pragma unroll
      for (int j = 0; j < 16; ++j) acc[j] += ck * gW[k * 64 + u0 + j];
    }
#pragma unroll
    for (int k = 0; k < 3; ++k) {
      float ck = xv[k];
#pragma unroll
      for (int j = 0; j < 16; ++j) acc[j] += ck * gW[(64 + k) * 64 + u0 + j];
    }
#pragma unroll
    for (int j = 0; j < 16; ++j) {
      esa += acc[j] * as_[u0 + j];
      eda += acc[j] * ad_[u0 + j];
    }
    float4* o = (float4*)(hp + (size_t)row * 64 + u0);
#pragma unroll
    for (int j = 0; j < 4; ++j)
      o[j] = make_float4(acc[4 * j], acc[4 * j + 1], acc[4 * j + 2], acc[4 * j + 3]);
  }
  es[row] = esa;
  ed[row] = eda;
}

// segment-softmax attention + aggregate; writes sT (u, row) via LDS transpose
__global__ __launch_bounds__(256) void k_attn(float* ws, const float* gb) {
  const float* es = ws + OFF_ES;
  const float* ed = ws + OFF_ED;
  const float* hp = ws + OFF_HP;
  float* sT = ws + OFF_ST;
  const int* cnt = (const int*)(ws + OFF_CNT);
  const int* slot = (const int*)(ws + OFF_SLOT);
  int wave = threadIdx.x >> 6, lane = threadIdx.x & 63;
  int rowbase = blockIdx.x * 64;
  int b = rowbase / NN;
  int nbase = rowbase - b * NN;
  __shared__ float sL[64][65];
  float gbv = gb[lane];
  for (int rr = 0; rr < 16; ++rr) {
    int lr = wave * 16 + rr;
    int n = nbase + lr;
    int row = b * NN + n;
    int deg = min(cnt[n], CAP);
    float edv = ed[row];
    float m = -1e30f;
    for (int i = lane; i < deg; i += 64) {
      int si = slot[n * CAP + i];
      float e = es[b * NN + si] + edv;
      e = e > 0.f ? e : NEG * e;
      m = fmaxf(m, e);
    }
#pragma unroll
    for (int o = 32; o >= 1; o >>= 1) m = fmaxf(m, __shfl_xor(m, o, 64));
    float dsum = 0.f;
    for (int i = lane; i < deg; i += 64) {
      int si = slot[n * CAP + i];
      float e = es[b * NN + si] + edv;
      e = e > 0.f ? e : NEG * e;
      dsum += __expf(e - m);
    }
#pragma unroll
    for (int o = 32; o >= 1; o >>= 1) dsum += __shfl_xor(dsum, o, 64);
    float inv = 1.f / dsum;
    float acc = 0.f;
    for (int i = 0; i < deg; ++i) {
      int si = slot[n * CAP + i];
      float e = es[b * NN + si] + edv;
      e = e > 0.f ? e : NEG * e;
      float w = __expf(e - m) * inv;
      acc += w * hp[(size_t)(b * NN + si) * 64 + lane];
    }
    sL[lr][lane] = acc + gbv;
  }
  __syncthreads();
#pragma unroll 1
  for (int it = 0; it < 16; ++it) {
    int u = it * 4 + wave;
    sT[(size_t)u * BN + rowbase + lane] = sL[lane][u];
  }
}

// GRU cell: r,u = sigmoid([x,s]@g1W+b) ; c = tanh([x,r*s]@g2W+b) ; h = u*s+(1-u)*c
__global__ __launch_bounds__(256) void k_gru(float* ws, const float* g1W,
                                             const float* g1b, const float* g2W,
                                             const float* g2b, int t) {
  const float* sT = ws + OFF_ST;
  const float* xT = ws + OFF_XT;
  float* rsT = ws + OFF_HP;   // overlay on dead h'
  float* hT = ws + OFF_HT;
  int row = blockIdx.x * 256 + threadIdx.x;
  float xv[3];
#pragma unroll
  for (int k = 0; k < 3; ++k) xv[k] = xT[(t * 3 + k) * BN + row];
  // phase 1: r gates -> rsT
#pragma unroll 1
  for (int uc = 0; uc < 4; ++uc) {
    int u0 = uc * 16;
    float acc[16];
#pragma unroll
    for (int j = 0; j < 16; ++j) acc[j] = 0.f;
#pragma unroll
    for (int k = 0; k < 3; ++k) {
      float ck = xv[k];
#pragma unroll
      for (int j = 0; j < 16; ++j) acc[j] += ck * g1W[k * 128 + u0 + j];
    }
    for (int k = 0; k < 64; ++k) {
      float sk = sT[k * BN + row];
#pragma unroll
      for (int j = 0; j < 16; ++j) acc[j] += sk * g1W[(3 + k) * 128 + u0 + j];
    }
#pragma unroll
    for (int j = 0; j < 16; ++j) {
      int u = u0 + j;
      float r = 1.f / (1.f + __expf(-(acc[j] + g1b[u])));
      rsT[u * BN + row] = r * sT[u * BN + row];
    }
  }
  // phase 2: u gate (recomputed) + candidate c + state update
#pragma unroll 1
  for (int uc = 0; uc < 4; ++uc) {
    int u0 = uc * 16;
    float aU[16], aC[16];
#pragma unroll
    for (int j = 0; j < 16; ++j) { aU[j] = 0.f; aC[j] = 0.f; }
#pragma unroll
    for (int k = 0; k < 3; ++k) {
      float ck = xv[k];
#pragma unroll
      for (int j = 0; j < 16; ++j) {
        aU[j] += ck * g1W[k * 128 + 64 + u0 + j];
        aC[j] += ck * g2W[k * 64 + u0 + j];
      }
    }
    for (int k = 0; k < 64; ++k) {
      float sk = sT[k * BN + row];
      float rk = rsT[k * BN + row];
#pragma unroll
      for (int j = 0; j < 16; ++j) {
        aU[j] += sk * g1W[(3 + k) * 128 + 64 + u0 + j];
        aC[j] += rk * g2W[(3 + k) * 64 + u0 + j];
      }
    }
#pragma unroll
    for (int j = 0; j < 16; ++j) {
      int u = u0 + j;
      float ug = 1.f / (1.f + __expf(-(aU[j] + g1b[64 + u])));
      float z = aC[j] + g2b[u];
      float c = 1.f - 2.f / (__expf(2.f * z) + 1.f);
      float sv = sT[u * BN + row];
      hT[u * BN + row] = ug * sv + (1.f - ug) * c;
    }
  }
}

__global__ __launch_bounds__(256) void k_out(const float* ws, const float* oW,
                                             const float* ob, float* out) {
  const float* hT = ws + OFF_HT;
  int row = blockIdx.x * 256 + threadIdx.x;
  float a0 = ob[0], a1 = ob[1], a2 = ob[2];
  for (int k = 0; k < 64; ++k) {
    float hk = hT[k * BN + row];
    a0 += hk * oW[k * 3 + 0];
    a1 += hk * oW[k * 3 + 1];
    a2 += hk * oW[k * 3 + 2];
  }
  out[row * 3 + 0] = a0;
  out[row * 3 + 1] = a1;
  out[row * 3 + 2] = a2;
}

extern "C" void kernel_launch(void* const* d_in, const int* in_sizes, int n_in,
                              void* d_out, int out_size, void* d_ws, size_t ws_size,
                              hipStream_t stream) {
  const float* x = (const float*)d_in[0];
  const int* src = (const int*)d_in[1];
  const int* dst = (const int*)d_in[2];
  const float* gatW = (const float*)d_in[3];
  const float* asrc = (const float*)d_in[4];
  const float* adst = (const float*)d_in[5];
  const float* gatb = (const float*)d_in[6];
  const float* g1W = (const float*)d_in[7];
  const float* g1b = (const float*)d_in[8];
  const float* g2W = (const float*)d_in[9];
  const float* g2b = (const float*)d_in[10];
  const float* oW = (const float*)d_in[11];
  const float* ob = (const float*)d_in[12];
  float* ws = (float*)d_ws;
  float* out = (float*)d_out;

  hipMemsetAsync(ws + OFF_CNT, 0, NN * sizeof(int), stream);
  hipMemsetAsync(ws + OFF_HT, 0, (size_t)64 * BN * sizeof(float), stream);
  k_conv_x<<<(12 * BN) / 256, 256, 0, stream>>>(x, ws + OFF_XT);
  k_fill<<<(EE + NN) / 256, 256, 0, stream>>>(src, dst, (int*)(ws + OFF_CNT),
                                              (int*)(ws + OFF_SLOT));
  for (int t = 0; t < TT; ++t) {
    k_gat<<<BN / 256, 256, 0, stream>>>(ws, gatW, asrc, adst, t);
    k_attn<<<BN / 64, 256, 0, stream>>>(ws, gatb);
    k_gru<<<BN / 256, 256, 0, stream>>>(ws, g1W, g1b, g2W, g2b, t);
  }
  k_out<<<BN / 256, 256, 0, stream>>>(ws, oW, ob, out);
}

// Round 3
// 542.226 us; speedup vs baseline: 2.4924x; 2.4924x over previous
//
#include <hip/hip_runtime.h>
#include <hip/hip_bf16.h>

#define BB 8
#define TT 4
#define NN 4096
#define UU 64
#define EE 65536
#define BN (BB*NN)   // 32768
#define CAP 64
#define NEG 0.2f

// ws layout (float offsets)
#define OFF_XT   0         // 12*BN   (t,f,row)
#define OFF_HT   393216    // 64*BN   (u,row)
#define OFF_HP   2490368   // BN*64   row-major h'
#define OFF_ES   4587520   // BN
#define OFF_ED   4620288   // BN
#define OFF_ST   4653056   // 64*BN   (u,row)
#define OFF_CNT  6750208   // NN ints
#define OFF_SLOT 6754304   // NN*CAP ints  (ends 7016448 floats = 28.07 MB)

__global__ __launch_bounds__(256) void k_conv_x(const float* x, float* xT) {
  int i = blockIdx.x * 256 + threadIdx.x;     // < 12*BN
  int r = i & (BN - 1);
  int tf = i >> 15;
  int t = tf / 3, f = tf - 3 * t;
  int b = r >> 12, n = r & (NN - 1);
  xT[i] = x[(((b * TT + t) * NN + n) * 3) + f];
}

__global__ __launch_bounds__(256) void k_fill(const int* src, const int* dst,
                                              int* cnt, int* slot) {
  int i = blockIdx.x * 256 + threadIdx.x;
  if (i < EE) {
    int d = dst[i];
    int p = atomicAdd(&cnt[d], 1);
    if (p < CAP) slot[d * CAP + p] = src[i];
  } else if (i < EE + NN) {
    int n = i - EE;
    int p = atomicAdd(&cnt[n], 1);
    if (p < CAP) slot[n * CAP + p] = n;
  }
}

// h' = [h, x_t] @ gat_W ; es = h'.a_src ; ed = h'.a_dst
// block: 64 rows x 4 u-chunk waves. grid = BN/64 = 512.
__global__ __launch_bounds__(256) void k_gat(float* ws, const float* gW,
                                             const float* as_, const float* ad_,
                                             int t, int hzero) {
  const float* hT = ws + OFF_HT;
  const float* xT = ws + OFF_XT;
  float* hp = ws + OFF_HP;
  float* es = ws + OFF_ES;
  float* ed = ws + OFF_ED;
  int wave = threadIdx.x >> 6, lane = threadIdx.x & 63;
  int rowbase = blockIdx.x * 64;
  int row = rowbase + lane;
  int u0 = wave * 16;
  float acc[16];
#pragma unroll
  for (int j = 0; j < 16; ++j) acc[j] = 0.f;
  if (!hzero) {
    for (int k = 0; k < 64; ++k) {
      float ck = hT[(size_t)k * BN + row];
#pragma unroll
      for (int j = 0; j < 16; ++j) acc[j] += ck * gW[k * 64 + u0 + j];
    }
  }
#pragma unroll
  for (int k = 0; k < 3; ++k) {
    float ck = xT[(t * 3 + k) * BN + row];
#pragma unroll
    for (int j = 0; j < 16; ++j) acc[j] += ck * gW[(64 + k) * 64 + u0 + j];
  }
  float esa = 0.f, eda = 0.f;
#pragma unroll
  for (int j = 0; j < 16; ++j) {
    esa += acc[j] * as_[u0 + j];
    eda += acc[j] * ad_[u0 + j];
  }
  float4* o = (float4*)(hp + (size_t)row * 64 + u0);
#pragma unroll
  for (int j = 0; j < 4; ++j)
    o[j] = make_float4(acc[4 * j], acc[4 * j + 1], acc[4 * j + 2], acc[4 * j + 3]);
  __shared__ float esL[4][64], edL[4][64];
  esL[wave][lane] = esa;
  edL[wave][lane] = eda;
  __syncthreads();
  if (wave == 0)
    es[row] = esL[0][lane] + esL[1][lane] + esL[2][lane] + esL[3][lane];
  else if (wave == 1)
    ed[row] = edL[0][lane] + edL[1][lane] + edL[2][lane] + edL[3][lane];
}

// segment-softmax attention + aggregate; 1024 threads, 16 waves, 4 rows/wave.
// grid = BN/64 = 512. writes sT (u,row) via LDS transpose.
__global__ __launch_bounds__(1024) void k_attn(float* ws, const float* gb) {
  const float* es = ws + OFF_ES;
  const float* ed = ws + OFF_ED;
  const float* hp = ws + OFF_HP;
  float* sT = ws + OFF_ST;
  const int* cnt = (const int*)(ws + OFF_CNT);
  const int* slot = (const int*)(ws + OFF_SLOT);
  int wave = threadIdx.x >> 6, lane = threadIdx.x & 63;
  int rowbase = blockIdx.x * 64;
  int b = rowbase / NN;
  int nbase = rowbase - b * NN;
  __shared__ float sL[64][65];
  float gbv = gb[lane];
#pragma unroll 1
  for (int rr = 0; rr < 4; ++rr) {
    int lr = wave * 4 + rr;
    int n = nbase + lr;
    int row = b * NN + n;
    int deg = min(cnt[n], CAP);
    float edv = ed[row];
    int sl = (lane < deg) ? slot[n * CAP + lane] : 0;
    float e;
    if (lane < deg) {
      e = es[b * NN + sl] + edv;
      e = e > 0.f ? e : NEG * e;
    } else {
      e = -1e30f;
    }
    float m = e;
#pragma unroll
    for (int o = 32; o >= 1; o >>= 1) m = fmaxf(m, __shfl_xor(m, o, 64));
    float w = (lane < deg) ? __expf(e - m) : 0.f;
    float dsum = w;
#pragma unroll
    for (int o = 32; o >= 1; o >>= 1) dsum += __shfl_xor(dsum, o, 64);
    w *= 1.f / dsum;
    float acc = 0.f;
    for (int i = 0; i < deg; ++i) {
      int si = __shfl(sl, i, 64);
      float wv = __shfl(w, i, 64);
      acc += wv * hp[(size_t)(b * NN + si) * 64 + lane];
    }
    sL[lr][lane] = acc + gbv;
  }
  __syncthreads();
#pragma unroll
  for (int it = 0; it < 4; ++it) {
    int u = wave * 4 + it;
    sT[(size_t)u * BN + rowbase + lane] = sL[lane][u];
  }
}

// GRU cell, block: 64 rows x 4 u-chunk waves, s/rs staged in LDS. grid 512.
__global__ __launch_bounds__(256) void k_gru(float* ws, const float* g1W,
                                             const float* g1b, const float* g2W,
                                             const float* g2b, int t) {
  const float* sT = ws + OFF_ST;
  const float* xT = ws + OFF_XT;
  float* hT = ws + OFF_HT;
  int wave = threadIdx.x >> 6, lane = threadIdx.x & 63;
  int rowbase = blockIdx.x * 64;
  int row = rowbase + lane;
  int u0 = wave * 16;
  __shared__ float sL[64][65];
  __shared__ float rsL[64][65];
#pragma unroll
  for (int kk = 0; kk < 16; ++kk) {
    int k = wave * 16 + kk;
    sL[k][lane] = sT[(size_t)k * BN + row];
  }
  __syncthreads();
  float xv[3];
#pragma unroll
  for (int k = 0; k < 3; ++k) xv[k] = xT[(t * 3 + k) * BN + row];
  // phase 1: r gates for u in [u0, u0+16)
  float aR[16];
#pragma unroll
  for (int j = 0; j < 16; ++j) aR[j] = 0.f;
#pragma unroll
  for (int k = 0; k < 3; ++k) {
    float ck = xv[k];
#pragma unroll
    for (int j = 0; j < 16; ++j) aR[j] += ck * g1W[k * 128 + u0 + j];
  }
  for (int k = 0; k < 64; ++k) {
    float sk = sL[k][lane];
#pragma unroll
    for (int j = 0; j < 16; ++j) aR[j] += sk * g1W[(3 + k) * 128 + u0 + j];
  }
#pragma unroll
  for (int j = 0; j < 16; ++j) {
    int u = u0 + j;
    float r = 1.f / (1.f + __expf(-(aR[j] + g1b[u])));
    rsL[u][lane] = r * sL[u][lane];
  }
  __syncthreads();
  // phase 2: u gate + candidate + state update
  float aU[16], aC[16];
#pragma unroll
  for (int j = 0; j < 16; ++j) { aU[j] = 0.f; aC[j] = 0.f; }
#pragma unroll
  for (int k = 0; k < 3; ++k) {
    float ck = xv[k];
#pragma unroll
    for (int j = 0; j < 16; ++j) {
      aU[j] += ck * g1W[k * 128 + 64 + u0 + j];
      aC[j] += ck * g2W[k * 64 + u0 + j];
    }
  }
  for (int k = 0; k < 64; ++k) {
    float sk = sL[k][lane];
    float rk = rsL[k][lane];
#pragma unroll
    for (int j = 0; j < 16; ++j) {
      aU[j] += sk * g1W[(3 + k) * 128 + 64 + u0 + j];
      aC[j] += rk * g2W[(3 + k) * 64 + u0 + j];
    }
  }
#pragma unroll
  for (int j = 0; j < 16; ++j) {
    int u = u0 + j;
    float ug = 1.f / (1.f + __expf(-(aU[j] + g1b[64 + u])));
    float z = aC[j] + g2b[u];
    float c = 1.f - 2.f / (__expf(2.f * z) + 1.f);
    hT[(size_t)u * BN + row] = ug * sL[u][lane] + (1.f - ug) * c;
  }
}

__global__ __launch_bounds__(256) void k_out(const float* ws, const float* oW,
                                             const float* ob, float* out) {
  const float* hT = ws + OFF_HT;
  int row = blockIdx.x * 256 + threadIdx.x;
  float a0 = ob[0], a1 = ob[1], a2 = ob[2];
  for (int k = 0; k < 64; ++k) {
    float hk = hT[(size_t)k * BN + row];
    a0 += hk * oW[k * 3 + 0];
    a1 += hk * oW[k * 3 + 1];
    a2 += hk * oW[k * 3 + 2];
  }
  out[row * 3 + 0] = a0;
  out[row * 3 + 1] = a1;
  out[row * 3 + 2] = a2;
}

extern "C" void kernel_launch(void* const* d_in, const int* in_sizes, int n_in,
                              void* d_out, int out_size, void* d_ws, size_t ws_size,
                              hipStream_t stream) {
  const float* x = (const float*)d_in[0];
  const int* src = (const int*)d_in[1];
  const int* dst = (const int*)d_in[2];
  const float* gatW = (const float*)d_in[3];
  const float* asrc = (const float*)d_in[4];
  const float* adst = (const float*)d_in[5];
  const float* gatb = (const float*)d_in[6];
  const float* g1W = (const float*)d_in[7];
  const float* g1b = (const float*)d_in[8];
  const float* g2W = (const float*)d_in[9];
  const float* g2b = (const float*)d_in[10];
  const float* oW = (const float*)d_in[11];
  const float* ob = (const float*)d_in[12];
  float* ws = (float*)d_ws;
  float* out = (float*)d_out;

  hipMemsetAsync(ws + OFF_CNT, 0, NN * sizeof(int), stream);
  k_conv_x<<<(12 * BN) / 256, 256, 0, stream>>>(x, ws + OFF_XT);
  k_fill<<<(EE + NN) / 256, 256, 0, stream>>>(src, dst, (int*)(ws + OFF_CNT),
                                              (int*)(ws + OFF_SLOT));
  for (int t = 0; t < TT; ++t) {
    k_gat<<<BN / 64, 256, 0, stream>>>(ws, gatW, asrc, adst, t, t == 0 ? 1 : 0);
    k_attn<<<BN / 64, 1024, 0, stream>>>(ws, gatb);
    k_gru<<<BN / 64, 256, 0, stream>>>(ws, g1W, g1b, g2W, g2b, t);
  }
  k_out<<<BN / 256, 256, 0, stream>>>(ws, oW, ob, out);
}

// Round 4
// 353.136 us; speedup vs baseline: 3.8270x; 1.5355x over previous
//
#include <hip/hip_runtime.h>
#include <hip/hip_bf16.h>

#define BB 8
#define TT 4
#define NN 4096
#define UU 64
#define EE 65536
#define BN (BB*NN)   // 32768
#define CAP 64
#define NEG 0.2f

// ws layout (float offsets)
#define OFF_XT   0         // 12*BN   (t,f,row)
#define OFF_HT   393216    // 64*BN   (u,row)
#define OFF_HP   2490368   // BN*64 row-major h' ; overlaid by rs (u,row) in gru
#define OFF_ES   4587520   // BN
#define OFF_ED   4620288   // BN
#define OFF_ST   4653056   // 64*BN   (u,row)
#define OFF_CNT  6750208   // NN ints
#define OFF_SLOT 6754304   // NN*CAP ints  (ends 7016448 floats = 28.07 MB)

__global__ __launch_bounds__(256) void k_conv_x(const float* x, float* xT) {
  int i = blockIdx.x * 256 + threadIdx.x;     // < 12*BN
  int r = i & (BN - 1);
  int tf = i >> 15;
  int t = tf / 3, f = tf - 3 * t;
  int b = r >> 12, n = r & (NN - 1);
  xT[i] = x[(((b * TT + t) * NN + n) * 3) + f];
}

__global__ __launch_bounds__(256) void k_fill(const int* src, const int* dst,
                                              int* cnt, int* slot) {
  int i = blockIdx.x * 256 + threadIdx.x;
  if (i < EE) {
    int d = dst[i];
    int p = atomicAdd(&cnt[d], 1);
    if (p < CAP) slot[d * CAP + p] = src[i];
  } else if (i < EE + NN) {
    int n = i - EE;
    int p = atomicAdd(&cnt[n], 1);
    if (p < CAP) slot[n * CAP + p] = n;
  }
}

// h' = [h, x_t] @ gat_W ; es = h'.a_src ; ed = h'.a_dst
// 512 thr: 8 waves x 8 outputs, 64 rows/block. grid = BN/64 = 512.
__global__ __launch_bounds__(512) void k_gat(float* ws, const float* gW,
                                             const float* as_, const float* ad_,
                                             int t, int hzero) {
  const float* hT = ws + OFF_HT;
  const float* xT = ws + OFF_XT;
  float* hp = ws + OFF_HP;
  float* es = ws + OFF_ES;
  float* ed = ws + OFF_ED;
  int wave = __builtin_amdgcn_readfirstlane(threadIdx.x >> 6);
  int lane = threadIdx.x & 63;
  int row = blockIdx.x * 64 + lane;
  int u0 = wave * 8;
  float acc[8];
#pragma unroll
  for (int j = 0; j < 8; ++j) acc[j] = 0.f;
  if (!hzero) {
#pragma unroll 8
    for (int k = 0; k < 64; ++k) {
      float ck = hT[(size_t)k * BN + row];
#pragma unroll
      for (int j = 0; j < 8; ++j) acc[j] += ck * gW[k * 64 + u0 + j];
    }
  }
#pragma unroll
  for (int k = 0; k < 3; ++k) {
    float ck = xT[(t * 3 + k) * BN + row];
#pragma unroll
    for (int j = 0; j < 8; ++j) acc[j] += ck * gW[(64 + k) * 64 + u0 + j];
  }
  float esa = 0.f, eda = 0.f;
#pragma unroll
  for (int j = 0; j < 8; ++j) {
    esa += acc[j] * as_[u0 + j];
    eda += acc[j] * ad_[u0 + j];
  }
  float4* o = (float4*)(hp + (size_t)row * 64 + u0);
  o[0] = make_float4(acc[0], acc[1], acc[2], acc[3]);
  o[1] = make_float4(acc[4], acc[5], acc[6], acc[7]);
  __shared__ float esL[8][64], edL[8][64];
  esL[wave][lane] = esa;
  edL[wave][lane] = eda;
  __syncthreads();
  if (wave == 0) {
    float s = 0.f;
#pragma unroll
    for (int w = 0; w < 8; ++w) s += esL[w][lane];
    es[row] = s;
  } else if (wave == 1) {
    float s = 0.f;
#pragma unroll
    for (int w = 0; w < 8; ++w) s += edL[w][lane];
    ed[row] = s;
  }
}

// segment-softmax attention + aggregate; 1024 thr, 16 waves, 4 rows/wave.
// grid = 512. gather loop unrolled by 8 to batch loads. writes sT via LDS transpose.
__global__ __launch_bounds__(1024) void k_attn(float* ws, const float* gb) {
  const float* es = ws + OFF_ES;
  const float* ed = ws + OFF_ED;
  const float* hp = ws + OFF_HP;
  float* sT = ws + OFF_ST;
  const int* cnt = (const int*)(ws + OFF_CNT);
  const int* slot = (const int*)(ws + OFF_SLOT);
  int wave = __builtin_amdgcn_readfirstlane(threadIdx.x >> 6);
  int lane = threadIdx.x & 63;
  int rowbase = blockIdx.x * 64;
  int b = rowbase / NN;
  int nbase = rowbase - b * NN;
  __shared__ float sL[64][65];
  float gbv = gb[lane];
#pragma unroll 1
  for (int rr = 0; rr < 4; ++rr) {
    int lr = wave * 4 + rr;
    int n = nbase + lr;
    int row = b * NN + n;
    int deg = min(cnt[n], CAP);
    float edv = ed[row];
    int sl = (lane < deg) ? slot[n * CAP + lane] : 0;
    float e;
    if (lane < deg) {
      e = es[b * NN + sl] + edv;
      e = e > 0.f ? e : NEG * e;
    } else {
      e = -1e30f;
    }
    float m = e;
#pragma unroll
    for (int o = 32; o >= 1; o >>= 1) m = fmaxf(m, __shfl_xor(m, o, 64));
    float w = (lane < deg) ? __expf(e - m) : 0.f;
    float dsum = w;
#pragma unroll
    for (int o = 32; o >= 1; o >>= 1) dsum += __shfl_xor(dsum, o, 64);
    w *= 1.f / dsum;
    float acc = 0.f;
#pragma unroll 1
    for (int i0 = 0; i0 < deg; i0 += 8) {
      int sis[8];
      float wv[8];
#pragma unroll
      for (int j = 0; j < 8; ++j) {
        int i = i0 + j;
        sis[j] = __shfl(sl, i, 64);
        float t_ = __shfl(w, i, 64);
        wv[j] = (i < deg) ? t_ : 0.f;
      }
      float v[8];
#pragma unroll
      for (int j = 0; j < 8; ++j)
        v[j] = hp[(size_t)(b * NN + sis[j]) * 64 + lane];
#pragma unroll
      for (int j = 0; j < 8; ++j) acc += wv[j] * v[j];
    }
    sL[lr][lane] = acc + gbv;
  }
  __syncthreads();
#pragma unroll
  for (int it = 0; it < 4; ++it) {
    int u = wave * 4 + it;
    sT[(size_t)u * BN + rowbase + lane] = sL[lane][u];
  }
}

// GRU part 1: r = sigmoid([x,s]@g1W[:, :64] + b); rs[u][row] = r*s
// 512 thr: 8 waves x 8 outputs. grid = 512.
__global__ __launch_bounds__(512) void k_gru1(float* ws, const float* g1W,
                                              const float* g1b, int t) {
  const float* sT = ws + OFF_ST;
  const float* xT = ws + OFF_XT;
  float* rs = ws + OFF_HP;   // overlay on dead h'
  int wave = __builtin_amdgcn_readfirstlane(threadIdx.x >> 6);
  int lane = threadIdx.x & 63;
  int row = blockIdx.x * 64 + lane;
  int u0 = wave * 8;
  float aR[8];
#pragma unroll
  for (int j = 0; j < 8; ++j) aR[j] = 0.f;
#pragma unroll
  for (int k = 0; k < 3; ++k) {
    float ck = xT[(t * 3 + k) * BN + row];
#pragma unroll
    for (int j = 0; j < 8; ++j) aR[j] += ck * g1W[k * 128 + u0 + j];
  }
#pragma unroll 8
  for (int k = 0; k < 64; ++k) {
    float sk = sT[(size_t)k * BN + row];
#pragma unroll
    for (int j = 0; j < 8; ++j) aR[j] += sk * g1W[(3 + k) * 128 + u0 + j];
  }
#pragma unroll
  for (int j = 0; j < 8; ++j) {
    int u = u0 + j;
    float r = 1.f / (1.f + __expf(-(aR[j] + g1b[u])));
    rs[(size_t)u * BN + row] = r * sT[(size_t)u * BN + row];
  }
}

// GRU part 2: ug = sigmoid([x,s]@g1W[:,64:]+b); c = tanh([x,rs]@g2W+b);
// h = ug*s + (1-ug)*c.  512 thr: 8 waves x 8 outputs. grid = 512.
__global__ __launch_bounds__(512) void k_gru2(float* ws, const float* g1W,
                                              const float* g1b, const float* g2W,
                                              const float* g2b, int t) {
  const float* sT = ws + OFF_ST;
  const float* xT = ws + OFF_XT;
  const float* rs = ws + OFF_HP;
  float* hT = ws + OFF_HT;
  int wave = __builtin_amdgcn_readfirstlane(threadIdx.x >> 6);
  int lane = threadIdx.x & 63;
  int row = blockIdx.x * 64 + lane;
  int u0 = wave * 8;
  float aU[8], aC[8];
#pragma unroll
  for (int j = 0; j < 8; ++j) { aU[j] = 0.f; aC[j] = 0.f; }
#pragma unroll
  for (int k = 0; k < 3; ++k) {
    float ck = xT[(t * 3 + k) * BN + row];
#pragma unroll
    for (int j = 0; j < 8; ++j) {
      aU[j] += ck * g1W[k * 128 + 64 + u0 + j];
      aC[j] += ck * g2W[k * 64 + u0 + j];
    }
  }
#pragma unroll 4
  for (int k = 0; k < 64; ++k) {
    float sk = sT[(size_t)k * BN + row];
    float rk = rs[(size_t)k * BN + row];
#pragma unroll
    for (int j = 0; j < 8; ++j) {
      aU[j] += sk * g1W[(3 + k) * 128 + 64 + u0 + j];
      aC[j] += rk * g2W[(3 + k) * 64 + u0 + j];
    }
  }
#pragma unroll
  for (int j = 0; j < 8; ++j) {
    int u = u0 + j;
    float ug = 1.f / (1.f + __expf(-(aU[j] + g1b[64 + u])));
    float z = aC[j] + g2b[u];
    float c = 1.f - 2.f / (__expf(2.f * z) + 1.f);
    float sv = sT[(size_t)u * BN + row];
    hT[(size_t)u * BN + row] = ug * sv + (1.f - ug) * c;
  }
}

__global__ __launch_bounds__(256) void k_out(const float* ws, const float* oW,
                                             const float* ob, float* out) {
  const float* hT = ws + OFF_HT;
  int row = blockIdx.x * 256 + threadIdx.x;
  float a0 = ob[0], a1 = ob[1], a2 = ob[2];
#pragma unroll 8
  for (int k = 0; k < 64; ++k) {
    float hk = hT[(size_t)k * BN + row];
    a0 += hk * oW[k * 3 + 0];
    a1 += hk * oW[k * 3 + 1];
    a2 += hk * oW[k * 3 + 2];
  }
  out[row * 3 + 0] = a0;
  out[row * 3 + 1] = a1;
  out[row * 3 + 2] = a2;
}

extern "C" void kernel_launch(void* const* d_in, const int* in_sizes, int n_in,
                              void* d_out, int out_size, void* d_ws, size_t ws_size,
                              hipStream_t stream) {
  const float* x = (const float*)d_in[0];
  const int* src = (const int*)d_in[1];
  const int* dst = (const int*)d_in[2];
  const float* gatW = (const float*)d_in[3];
  const float* asrc = (const float*)d_in[4];
  const float* adst = (const float*)d_in[5];
  const float* gatb = (const float*)d_in[6];
  const float* g1W = (const float*)d_in[7];
  const float* g1b = (const float*)d_in[8];
  const float* g2W = (const float*)d_in[9];
  const float* g2b = (const float*)d_in[10];
  const float* oW = (const float*)d_in[11];
  const float* ob = (const float*)d_in[12];
  float* ws = (float*)d_ws;
  float* out = (float*)d_out;

  hipMemsetAsync(ws + OFF_CNT, 0, NN * sizeof(int), stream);
  k_conv_x<<<(12 * BN) / 256, 256, 0, stream>>>(x, ws + OFF_XT);
  k_fill<<<(EE + NN) / 256, 256, 0, stream>>>(src, dst, (int*)(ws + OFF_CNT),
                                              (int*)(ws + OFF_SLOT));
  for (int t = 0; t < TT; ++t) {
    k_gat<<<BN / 64, 512, 0, stream>>>(ws, gatW, asrc, adst, t, t == 0 ? 1 : 0);
    k_attn<<<BN / 64, 1024, 0, stream>>>(ws, gatb);
    k_gru1<<<BN / 64, 512, 0, stream>>>(ws, g1W, g1b, t);
    k_gru2<<<BN / 64, 512, 0, stream>>>(ws, g1W, g1b, g2W, g2b, t);
  }
  k_out<<<BN / 256, 256, 0, stream>>>(ws, oW, ob, out);
}

// Round 6
// 301.138 us; speedup vs baseline: 4.4878x; 1.1727x over previous
//
#include <hip/hip_runtime.h>
#include <hip/hip_bf16.h>

#define BB 8
#define TT 4
#define NN 4096
#define UU 64
#define EE 65536
#define BN (BB*NN)   // 32768
#define CAP 64
#define NEG 0.2f

// ws layout (float offsets); hp/es/ed ping-pong by t parity
#define OFF_XT   0                      // 12*BN  (t,f,row)
#define OFF_HP0  (12*BN)                // BN*64 row-major h'
#define OFF_HP1  (OFF_HP0 + 64*BN)
#define OFF_ES0  (OFF_HP1 + 64*BN)     // BN
#define OFF_ES1  (OFF_ES0 + BN)
#define OFF_ED0  (OFF_ES1 + BN)
#define OFF_ED1  (OFF_ED0 + BN)
#define OFF_CNT  (OFF_ED1 + BN)        // NN ints
#define OFF_SLOT (OFF_CNT + NN)        // NN*CAP ints (ends ~19.9 MB)

__global__ __launch_bounds__(256) void k_conv_x(const float* x, float* xT) {
  int i = blockIdx.x * 256 + threadIdx.x;     // < 12*BN
  int r = i & (BN - 1);
  int tf = i >> 15;
  int t = tf / 3, f = tf - 3 * t;
  int b = r >> 12, n = r & (NN - 1);
  xT[i] = x[(((b * TT + t) * NN + n) * 3) + f];
}

__global__ __launch_bounds__(256) void k_fill(const int* src, const int* dst,
                                              int* cnt, int* slot) {
  int i = blockIdx.x * 256 + threadIdx.x;
  if (i < EE) {
    int d = dst[i];
    int p = atomicAdd(&cnt[d], 1);
    if (p < CAP) slot[d * CAP + p] = src[i];
  } else if (i < EE + NN) {
    int n = i - EE;
    int p = atomicAdd(&cnt[n], 1);
    if (p < CAP) slot[n * CAP + p] = n;
  }
}

// GAT at t=0 (h == 0): h' = x_0 @ gat_W[64:67]; es/ed. Writes buffer 0.
__global__ __launch_bounds__(512) void k_gat0(float* ws, const float* gW,
                                              const float* as_, const float* ad_) {
  const float* xT = ws + OFF_XT;
  float* hp = ws + OFF_HP0;
  float* es = ws + OFF_ES0;
  float* ed = ws + OFF_ED0;
  int wave = __builtin_amdgcn_readfirstlane(threadIdx.x >> 6);
  int lane = threadIdx.x & 63;
  int row = blockIdx.x * 64 + lane;
  int u0 = wave * 8;
  float acc[8];
#pragma unroll
  for (int j = 0; j < 8; ++j) acc[j] = 0.f;
#pragma unroll
  for (int k = 0; k < 3; ++k) {
    float ck = xT[k * BN + row];   // t=0
#pragma unroll
    for (int j = 0; j < 8; ++j) acc[j] += ck * gW[(64 + k) * 64 + u0 + j];
  }
  float esa = 0.f, eda = 0.f;
#pragma unroll
  for (int j = 0; j < 8; ++j) {
    esa += acc[j] * as_[u0 + j];
    eda += acc[j] * ad_[u0 + j];
  }
  float4* o = (float4*)(hp + (size_t)row * 64 + u0);
  o[0] = make_float4(acc[0], acc[1], acc[2], acc[3]);
  o[1] = make_float4(acc[4], acc[5], acc[6], acc[7]);
  __shared__ float esL[8][64], edL[8][64];
  esL[wave][lane] = esa;
  edL[wave][lane] = eda;
  __syncthreads();
  if (wave == 0) {
    float s = 0.f;
#pragma unroll
    for (int w = 0; w < 8; ++w) s += esL[w][lane];
    es[row] = s;
  } else if (wave == 1) {
    float s = 0.f;
#pragma unroll
    for (int w = 0; w < 8; ++w) s += edL[w][lane];
    ed[row] = s;
  }
}

// Fused step: attn(t) -> GRU(t) -> [GAT(t+1) | out head].
// 512 thr, 8 waves, 64 rows/block, grid = BN/64 = 512.
// Reads hp/es/ed parity (t&1); writes parity (~t&1).
// LDS tiles sL/rsL are [u][row_local] throughout.
__global__ __launch_bounds__(512) void k_step(
    float* ws, const float* gb, const float* g1W, const float* g1b,
    const float* g2W, const float* g2b, const float* gW, const float* as_,
    const float* ad_, const float* oW, const float* ob, float* out, int t,
    int last) {
  const float* xT = ws + OFF_XT;
  int pr = t & 1;
  const float* hpR = ws + (pr ? OFF_HP1 : OFF_HP0);
  const float* esR = ws + (pr ? OFF_ES1 : OFF_ES0);
  const float* edR = ws + (pr ? OFF_ED1 : OFF_ED0);
  float* hpW = ws + (pr ? OFF_HP0 : OFF_HP1);
  float* esW = ws + (pr ? OFF_ES0 : OFF_ES1);
  float* edW = ws + (pr ? OFF_ED0 : OFF_ED1);
  const int* cnt = (const int*)(ws + OFF_CNT);
  const int* slot = (const int*)(ws + OFF_SLOT);

  int wave = __builtin_amdgcn_readfirstlane(threadIdx.x >> 6);
  int lane = threadIdx.x & 63;
  int rowbase = blockIdx.x * 64;
  int b = rowbase / NN;
  int nbase = rowbase - b * NN;
  __shared__ float sL[64][65];
  __shared__ float rsL[64][65];
  __shared__ float redA[8][64], redB[8][64];
  float gbv = gb[lane];   // lane = u in P1

  // ---- P1: attention, 8 rows per wave; store TRANSPOSED -> sL[u][row] ----
#pragma unroll 1
  for (int rr = 0; rr < 8; ++rr) {
    int lr = wave * 8 + rr;
    int n = nbase + lr;
    int grow = b * NN + n;
    int deg = min(cnt[n], CAP);
    float edv = edR[grow];
    int sl = (lane < deg) ? slot[n * CAP + lane] : 0;
    float e;
    if (lane < deg) {
      e = esR[b * NN + sl] + edv;
      e = e > 0.f ? e : NEG * e;
    } else {
      e = -1e30f;
    }
    float m = e;
#pragma unroll
    for (int o = 32; o >= 1; o >>= 1) m = fmaxf(m, __shfl_xor(m, o, 64));
    float w = (lane < deg) ? __expf(e - m) : 0.f;
    float dsum = w;
#pragma unroll
    for (int o = 32; o >= 1; o >>= 1) dsum += __shfl_xor(dsum, o, 64);
    w *= 1.f / dsum;
    float acc = 0.f;
#pragma unroll 1
    for (int i0 = 0; i0 < deg; i0 += 8) {
      int sis[8];
      float wv[8];
#pragma unroll
      for (int j = 0; j < 8; ++j) {
        int i = i0 + j;
        sis[j] = __shfl(sl, i, 64);
        float t_ = __shfl(w, i, 64);
        wv[j] = (i < deg) ? t_ : 0.f;
      }
      float v[8];
#pragma unroll
      for (int j = 0; j < 8; ++j)
        v[j] = hpR[(size_t)(b * NN + sis[j]) * 64 + lane];
#pragma unroll
      for (int j = 0; j < 8; ++j) acc += wv[j] * v[j];
    }
    sL[lane][lr] = acc + gbv;   // transpose: [u=lane][row_local=lr]
  }
  __syncthreads();

  int row = rowbase + lane;
  int u0 = wave * 8;
  float xv[3];
#pragma unroll
  for (int k = 0; k < 3; ++k) xv[k] = xT[(t * 3 + k) * BN + row];

  // ---- P2: r gate -> rsL ----
  float aR[8];
#pragma unroll
  for (int j = 0; j < 8; ++j) aR[j] = 0.f;
#pragma unroll
  for (int k = 0; k < 3; ++k) {
    float ck = xv[k];
#pragma unroll
    for (int j = 0; j < 8; ++j) aR[j] += ck * g1W[k * 128 + u0 + j];
  }
#pragma unroll 8
  for (int k = 0; k < 64; ++k) {
    float sk = sL[k][lane];
#pragma unroll
    for (int j = 0; j < 8; ++j) aR[j] += sk * g1W[(3 + k) * 128 + u0 + j];
  }
#pragma unroll
  for (int j = 0; j < 8; ++j) {
    int u = u0 + j;
    float r = 1.f / (1.f + __expf(-(aR[j] + g1b[u])));
    rsL[u][lane] = r * sL[u][lane];
  }
  __syncthreads();

  // ---- P3: u gate + candidate + state update (h in regs) ----
  float aU[8], aC[8];
#pragma unroll
  for (int j = 0; j < 8; ++j) { aU[j] = 0.f; aC[j] = 0.f; }
#pragma unroll
  for (int k = 0; k < 3; ++k) {
    float ck = xv[k];
#pragma unroll
    for (int j = 0; j < 8; ++j) {
      aU[j] += ck * g1W[k * 128 + 64 + u0 + j];
      aC[j] += ck * g2W[k * 64 + u0 + j];
    }
  }
#pragma unroll 4
  for (int k = 0; k < 64; ++k) {
    float sk = sL[k][lane];
    float rk = rsL[k][lane];
#pragma unroll
    for (int j = 0; j < 8; ++j) {
      aU[j] += sk * g1W[(3 + k) * 128 + 64 + u0 + j];
      aC[j] += rk * g2W[(3 + k) * 64 + u0 + j];
    }
  }
  float hreg[8];
#pragma unroll
  for (int j = 0; j < 8; ++j) {
    int u = u0 + j;
    float ug = 1.f / (1.f + __expf(-(aU[j] + g1b[64 + u])));
    float z = aC[j] + g2b[u];
    float c = 1.f - 2.f / (__expf(2.f * z) + 1.f);
    hreg[j] = ug * sL[u][lane] + (1.f - ug) * c;
  }
  __syncthreads();

  // ---- P4: h -> sL (still [u][row]) ----
#pragma unroll
  for (int j = 0; j < 8; ++j) sL[u0 + j][lane] = hreg[j];
  __syncthreads();

  if (!last) {
    // ---- P5: GAT for step t+1 on in-LDS h ----
    float accG[8];
#pragma unroll
    for (int j = 0; j < 8; ++j) accG[j] = 0.f;
#pragma unroll 8
    for (int k = 0; k < 64; ++k) {
      float ck = sL[k][lane];
#pragma unroll
      for (int j = 0; j < 8; ++j) accG[j] += ck * gW[k * 64 + u0 + j];
    }
#pragma unroll
    for (int k = 0; k < 3; ++k) {
      float ck = xT[((t + 1) * 3 + k) * BN + row];
#pragma unroll
      for (int j = 0; j < 8; ++j) accG[j] += ck * gW[(64 + k) * 64 + u0 + j];
    }
    float esa = 0.f, eda = 0.f;
#pragma unroll
    for (int j = 0; j < 8; ++j) {
      esa += accG[j] * as_[u0 + j];
      eda += accG[j] * ad_[u0 + j];
    }
    float4* o = (float4*)(hpW + (size_t)row * 64 + u0);
    o[0] = make_float4(accG[0], accG[1], accG[2], accG[3]);
    o[1] = make_float4(accG[4], accG[5], accG[6], accG[7]);
    redA[wave][lane] = esa;
    redB[wave][lane] = eda;
    __syncthreads();
    if (wave == 0) {
      float s = 0.f;
#pragma unroll
      for (int w = 0; w < 8; ++w) s += redA[w][lane];
      esW[row] = s;
    } else if (wave == 1) {
      float s = 0.f;
#pragma unroll
      for (int w = 0; w < 8; ++w) s += redB[w][lane];
      edW[row] = s;
    }
  } else {
    // ---- P5': output head out[row,:] = h . oW + ob ----
    if (wave < 3) {
      float a = ob[wave];
#pragma unroll 8
      for (int k = 0; k < 64; ++k) a += sL[k][lane] * oW[k * 3 + wave];
      out[(size_t)row * 3 + wave] = a;
    }
  }
}

extern "C" void kernel_launch(void* const* d_in, const int* in_sizes, int n_in,
                              void* d_out, int out_size, void* d_ws, size_t ws_size,
                              hipStream_t stream) {
  const float* x = (const float*)d_in[0];
  const int* src = (const int*)d_in[1];
  const int* dst = (const int*)d_in[2];
  const float* gatW = (const float*)d_in[3];
  const float* asrc = (const float*)d_in[4];
  const float* adst = (const float*)d_in[5];
  const float* gatb = (const float*)d_in[6];
  const float* g1W = (const float*)d_in[7];
  const float* g1b = (const float*)d_in[8];
  const float* g2W = (const float*)d_in[9];
  const float* g2b = (const float*)d_in[10];
  const float* oW = (const float*)d_in[11];
  const float* ob = (const float*)d_in[12];
  float* ws = (float*)d_ws;
  float* out = (float*)d_out;

  hipMemsetAsync(ws + OFF_CNT, 0, NN * sizeof(int), stream);
  k_conv_x<<<(12 * BN) / 256, 256, 0, stream>>>(x, ws + OFF_XT);
  k_fill<<<(EE + NN) / 256, 256, 0, stream>>>(src, dst, (int*)(ws + OFF_CNT),
                                              (int*)(ws + OFF_SLOT));
  k_gat0<<<BN / 64, 512, 0, stream>>>(ws, gatW, asrc, adst);
  for (int t = 0; t < TT; ++t) {
    k_step<<<BN / 64, 512, 0, stream>>>(ws, gatb, g1W, g1b, g2W, g2b, gatW,
                                        asrc, adst, oW, ob, out, t,
                                        t == TT - 1 ? 1 : 0);
  }
}